// Round 10
// baseline (178.607 us; speedup 1.0000x reference)
//
#include <hip/hip_runtime.h>
#include <hip/hip_fp16.h>

#define NN 50000
#define BSHIFT 8
#define NBK ((NN + 255) >> 8)   // 196 buckets of 256 nodes
#define CHUNK 4096
#define CAP 8192

typedef __attribute__((ext_vector_type(8))) _Float16 f16x8;
typedef __attribute__((ext_vector_type(4))) float f32x4;

__device__ __forceinline__ float recw(unsigned r) {
    unsigned short us = (unsigned short)(r >> 16);
    __half h;
    __builtin_memcpy(&h, &us, 2);
    return __half2float(h);
}
__device__ __forceinline__ float2 h2f2(unsigned v) {
    __half2 h;
    __builtin_memcpy(&h, &v, 4);
    return __half22float2(h);
}
__device__ __forceinline__ unsigned f2h2(float a, float b) {
    __half2 h = __floats2half2_rn(a, b);
    unsigned u;
    __builtin_memcpy(&u, &h, 4);
    return u;
}
__device__ __forceinline__ f16x8 as_f16x8(uint4 v) {
    f16x8 r;
    __builtin_memcpy(&r, &v, 16);
    return r;
}
__device__ __forceinline__ unsigned short f2h1(float v) {
    __half h = __float2half(v);
    unsigned short us;
    __builtin_memcpy(&us, &h, 2);
    return us;
}

// ---------------- fat prep: bucket counts (y=0/1) + x->fp16 cvt + W pack (y=2) ----------------

__global__ __launch_bounds__(256) void fat_prep(const int* __restrict__ eiS, int Es,
                                                const int* __restrict__ eiD, int Ed,
                                                int* __restrict__ cntS,
                                                int* __restrict__ cntD,
                                                const float* __restrict__ x,
                                                unsigned* __restrict__ x16, int total4,
                                                const float* __restrict__ W1s,
                                                const float* __restrict__ W1d,
                                                const float* __restrict__ W2s,
                                                const float* __restrict__ W2d,
                                                unsigned short* __restrict__ Bp) {
    __shared__ int h[NBK];
    if (blockIdx.y < 2) {
        int rel = blockIdx.y;
        const int* dst = rel ? (eiD + Ed) : (eiS + Es);
        int E = rel ? Ed : Es;
        int* cnt = rel ? cntD : cntS;
        int base = blockIdx.x * CHUNK;
        if (base >= E) return;
        for (int i = threadIdx.x; i < NBK; i += 256) h[i] = 0;
        __syncthreads();
        int end = (base + CHUNK < E) ? base + CHUNK : E;
        for (int e = base + threadIdx.x; e < end; e += 256)
            atomicAdd(&h[dst[e] >> BSHIFT], 1);
        __syncthreads();
        for (int i = threadIdx.x; i < NBK; i += 256)
            if (h[i]) atomicAdd(&cnt[i], h[i]);
    } else {
        int i = blockIdx.x * 256 + threadIdx.x;
        if (i < total4) {
            float4 v = reinterpret_cast<const float4*>(x)[i];
            uint2 o;
            o.x = f2h2(v.x, v.y);
            o.y = f2h2(v.z, v.w);
            reinterpret_cast<uint2*>(x16)[i] = o;
        }
        if (blockIdx.x < 64) {
            int idx = blockIdx.x * 256 + threadIdx.x;  // < 16384
            int layer = idx >> 13;
            int rem = idx & 8191;
            int j = rem & 7;
            int l = (rem >> 3) & 63;
            int jt = (rem >> 9) & 3;
            int ks = rem >> 11;
            int k = ks * 32 + (l >> 4) * 8 + j;
            int col = jt * 16 + (l & 15);
            const float* Ws = layer ? W2s : W1s;
            const float* Wd = layer ? W2d : W1d;
            float v = (k < 64) ? Ws[k * 64 + col] : Wd[(k - 64) * 64 + col];
            Bp[idx] = f2h1(v);
        }
    }
}

// ---------------- pass B: scan bucket counts ----------------

__global__ __launch_bounds__(256) void bucket_scan(const int* __restrict__ cntS,
                                                   const int* __restrict__ cntD,
                                                   int* __restrict__ baseS,
                                                   int* __restrict__ baseD,
                                                   int* __restrict__ curS,
                                                   int* __restrict__ curD,
                                                   int* __restrict__ offsS,
                                                   int* __restrict__ offsD) {
    __shared__ int sA[256], sB[256];
    const int* cnt = blockIdx.x ? cntD : cntS;
    int* base = blockIdx.x ? baseD : baseS;
    int* cur  = blockIdx.x ? curD : curS;
    int* offs = blockIdx.x ? offsD : offsS;
    int t = threadIdx.x;
    int v = (t < NBK) ? cnt[t] : 0;
    sA[t] = v;
    __syncthreads();
    int* pin = sA; int* pout = sB;
    for (int st = 1; st < 256; st <<= 1) {
        int x = pin[t];
        if (t >= st) x += pin[t - st];
        pout[t] = x;
        __syncthreads();
        int* tmp = pin; pin = pout; pout = tmp;
    }
    int incl = pin[t];
    int excl = incl - v;
    if (t < NBK) { base[t] = excl; cur[t] = excl; }
    if (t == NBK - 1) { base[NBK] = incl; offs[NN] = incl; }
}

// ---------------- pass C: scatter packed records ----------------

__global__ __launch_bounds__(256) void bucket_scatter(const int* __restrict__ eiS, int Es,
                                                      const int* __restrict__ eiD, int Ed,
                                                      int* __restrict__ curS,
                                                      int* __restrict__ curD,
                                                      unsigned* __restrict__ recS,
                                                      unsigned* __restrict__ recD) {
    __shared__ int h[NBK];
    __shared__ int rb[NBK];
    int rel = blockIdx.y;
    const int* ei = rel ? eiD : eiS;
    int E = rel ? Ed : Es;
    int* cur = rel ? curD : curS;
    unsigned* rec = rel ? recD : recS;
    int base = blockIdx.x * CHUNK;
    if (base >= E) return;
    const int* src = ei;
    const int* dst = ei + E;
    int end = (base + CHUNK < E) ? base + CHUNK : E;

    for (int i = threadIdx.x; i < NBK; i += 256) h[i] = 0;
    __syncthreads();
    for (int e = base + threadIdx.x; e < end; e += 256)
        atomicAdd(&h[dst[e] >> BSHIFT], 1);
    __syncthreads();
    for (int i = threadIdx.x; i < NBK; i += 256) {
        int c = h[i];
        rb[i] = c ? atomicAdd(&cur[i], c) : 0;
    }
    __syncthreads();
    for (int i = threadIdx.x; i < NBK; i += 256) h[i] = 0;
    __syncthreads();
    for (int e = base + threadIdx.x; e < end; e += 256) {
        int d = dst[e];
        int s = src[e];
        int b = d >> BSHIFT;
        int p = atomicAdd(&h[b], 1);
        rec[rb[b] + p] = (unsigned)s | ((unsigned)(d & 255) << 16);
    }
}

// ---------------- pass D: per-bucket finalize ----------------

__global__ __launch_bounds__(256) void bucket_finalize(const int* __restrict__ baseS,
                                                       const int* __restrict__ baseD,
                                                       unsigned* __restrict__ recS,
                                                       unsigned* __restrict__ recD,
                                                       int* __restrict__ offsS,
                                                       int* __restrict__ offsD,
                                                       float* __restrict__ dinvS,
                                                       float* __restrict__ dinvD) {
    __shared__ unsigned recs[CAP];
    __shared__ int lc[256], sA[256], sB[256];
    int rel = blockIdx.y;
    const int* base = rel ? baseD : baseS;
    unsigned* rec = rel ? recD : recS;
    int* offs = rel ? offsD : offsS;
    float* dinv = rel ? dinvD : dinvS;
    int b = blockIdx.x;
    int b0 = base[b], b1 = base[b + 1];
    int cnt = b1 - b0;
    int t = threadIdx.x;
    lc[t] = 0;
    __syncthreads();
    for (int i = t; i < cnt; i += 256) {
        unsigned r = rec[b0 + i];
        if (i < CAP) recs[i] = r;
        atomicAdd(&lc[r >> 16], 1);
    }
    __syncthreads();
    int v = lc[t];
    int g = (b << BSHIFT) + t;
    if (g < NN) dinv[g] = rsqrtf((float)v + 1.0f);
    sA[t] = v;
    __syncthreads();
    int* pin = sA; int* pout = sB;
    for (int st = 1; st < 256; st <<= 1) {
        int x = pin[t];
        if (t >= st) x += pin[t - st];
        pout[t] = x;
        __syncthreads();
        int* tmp = pin; pin = pout; pout = tmp;
    }
    int excl = pin[t] - v;
    if (g < NN) offs[g] = b0 + excl;
    lc[t] = excl;
    __syncthreads();
    for (int i = t; i < cnt; i += 256) {
        unsigned r = (i < CAP) ? recs[i] : rec[b0 + i];
        int p = atomicAdd(&lc[r >> 16], 1);
        rec[b0 + p] = r & 0xFFFFu;
    }
}

// ---------------- pack: rec = src | half(dinv[src])<<16 ----------------

__global__ __launch_bounds__(256) void pack_rec(unsigned* __restrict__ recS, int Es,
                                                unsigned* __restrict__ recD, int Ed,
                                                const float* __restrict__ dinvS,
                                                const float* __restrict__ dinvD) {
    int i = blockIdx.x * 256 + threadIdx.x;
    if (i < Es) {
        unsigned s = recS[i] & 0xFFFFu;
        recS[i] = s | ((unsigned)f2h1(dinvS[s]) << 16);
    }
    if (i < Ed) {
        unsigned s = recD[i] & 0xFFFFu;
        recD[i] = s | ((unsigned)f2h1(dinvD[s]) << 16);
    }
}

// ---------------- gather -> fp16 A matrix [n,128] ----------------
// relation = blockIdx.y. Each 16-lane cluster owns ONE (node, rel): lane q owns
// feature quad exclusively -> NO cross-lane reduce, no redundant weight decode.
// 4 clusters/wave; while(__any) loop, unroll-4 -> 4 rec + 4 feat loads in flight.

__global__ __launch_bounds__(256) void gather_agg(const int* __restrict__ offsS,
                                                  const unsigned* __restrict__ recS,
                                                  const int* __restrict__ offsD,
                                                  const unsigned* __restrict__ recD,
                                                  const unsigned* __restrict__ feat,
                                                  const float* __restrict__ dinvS,
                                                  const float* __restrict__ dinvD,
                                                  unsigned* __restrict__ A, int n) {
    int rel = blockIdx.y;
    const int* __restrict__ offs = rel ? offsD : offsS;
    const unsigned* __restrict__ rec = rel ? recD : recS;
    const float* __restrict__ dinv = rel ? dinvD : dinvS;

    int wv = (blockIdx.x * 256 + threadIdx.x) >> 6;
    int lane = threadIdx.x & 63;
    int c = lane >> 4;        // cluster 0..3 -> node
    int q = lane & 15;        // feature quad: features 4q..4q+3
    int node = wv * 4 + c;
    if (node >= n) return;

    const uint2* featv = reinterpret_cast<const uint2*>(feat);  // row = 16 uint2

    float dv = dinv[node];
    int e0 = offs[node];
    int cnt = offs[node + 1] - e0;

    // self loop
    uint2 sv = featv[(size_t)node * 16 + q];
    float2 s0 = h2f2(sv.x), s1 = h2f2(sv.y);
    float a0 = dv * s0.x, a1 = dv * s0.y, a2 = dv * s1.x, a3 = dv * s1.y;

    int i = 0;
    while (__any(i < cnt)) {
#pragma unroll
        for (int k = 0; k < 4; k++) {
            int e = i + k;
            unsigned r = (e < cnt) ? rec[e0 + e] : 0u;   // r=0 -> w=+0.0, row 0 (hot)
            uint2 v = featv[(size_t)(r & 0xFFFFu) * 16 + q];
            float wt = recw(r);
            float2 f0 = h2f2(v.x), f1 = h2f2(v.y);
            a0 = fmaf(wt, f0.x, a0);
            a1 = fmaf(wt, f0.y, a1);
            a2 = fmaf(wt, f1.x, a2);
            a3 = fmaf(wt, f1.y, a3);
        }
        i += 4;
    }

    uint2 o;
    o.x = f2h2(dv * a0, dv * a1);
    o.y = f2h2(dv * a2, dv * a3);
    reinterpret_cast<uint2*>(A)[(size_t)node * 32 + rel * 16 + q] = o;
}

// ---------------- apply via fp16 MFMA: [n,128] @ [128,64], bias+relu epilogue ----------------

#define STORE_JT(ACC, JT)                                                     \
    {                                                                         \
        int colj = (JT) * 16 + lr;                                            \
        float bs = ba[colj] + bb[colj];                                       \
        _Pragma("unroll")                                                     \
        for (int r = 0; r < 4; r++) {                                         \
            float v = fmaxf(ACC[r] + bs, 0.0f);                               \
            outH[(size_t)(m0 + lh * 4 + r) * 64 + colj] = f2h1(v);            \
        }                                                                     \
    }

#define HEAD_JT(ACC, JT)                                                      \
    {                                                                         \
        int colj = (JT) * 16 + lr;                                            \
        float bs = ba[colj] + bb[colj];                                       \
        float w0 = Wlin[colj * 3 + 0];                                        \
        float w1 = Wlin[colj * 3 + 1];                                        \
        float w2 = Wlin[colj * 3 + 2];                                        \
        _Pragma("unroll")                                                     \
        for (int r = 0; r < 4; r++) {                                         \
            float v = fmaxf(ACC[r] + bs, 0.0f);                               \
            h0[r] = fmaf(v, w0, h0[r]);                                       \
            h1[r] = fmaf(v, w1, h1[r]);                                       \
            h2[r] = fmaf(v, w2, h2[r]);                                       \
        }                                                                     \
    }

template <int HEAD>
__global__ __launch_bounds__(256) void apply_mfma(const unsigned* __restrict__ A,
                                                  const unsigned short* __restrict__ Bp,
                                                  const float* __restrict__ ba,
                                                  const float* __restrict__ bb,
                                                  const float* __restrict__ Wlin,
                                                  const float* __restrict__ blin,
                                                  unsigned short* __restrict__ outH,
                                                  float* __restrict__ out3, int n) {
    int wid = (blockIdx.x * 256 + threadIdx.x) >> 6;
    int l = threadIdx.x & 63;
    int m0 = wid * 16;
    if (m0 >= n) return;
    int lr = l & 15;
    int lh = l >> 4;

    const uint4* Bv = reinterpret_cast<const uint4*>(Bp);
    f32x4 acc0 = {0.f, 0.f, 0.f, 0.f};
    f32x4 acc1 = {0.f, 0.f, 0.f, 0.f};
    f32x4 acc2 = {0.f, 0.f, 0.f, 0.f};
    f32x4 acc3 = {0.f, 0.f, 0.f, 0.f};

#pragma unroll
    for (int ks = 0; ks < 4; ks++) {
        uint4 av = *reinterpret_cast<const uint4*>(A + (size_t)(m0 + lr) * 64 + ks * 16 + lh * 4);
        f16x8 af = as_f16x8(av);
        uint4 b0 = Bv[(ks * 4 + 0) * 64 + l];
        uint4 b1 = Bv[(ks * 4 + 1) * 64 + l];
        uint4 b2 = Bv[(ks * 4 + 2) * 64 + l];
        uint4 b3 = Bv[(ks * 4 + 3) * 64 + l];
        acc0 = __builtin_amdgcn_mfma_f32_16x16x32_f16(af, as_f16x8(b0), acc0, 0, 0, 0);
        acc1 = __builtin_amdgcn_mfma_f32_16x16x32_f16(af, as_f16x8(b1), acc1, 0, 0, 0);
        acc2 = __builtin_amdgcn_mfma_f32_16x16x32_f16(af, as_f16x8(b2), acc2, 0, 0, 0);
        acc3 = __builtin_amdgcn_mfma_f32_16x16x32_f16(af, as_f16x8(b3), acc3, 0, 0, 0);
    }

    if (HEAD == 0) {
        STORE_JT(acc0, 0)
        STORE_JT(acc1, 1)
        STORE_JT(acc2, 2)
        STORE_JT(acc3, 3)
    } else {
        float h0[4] = {0.f, 0.f, 0.f, 0.f};
        float h1[4] = {0.f, 0.f, 0.f, 0.f};
        float h2[4] = {0.f, 0.f, 0.f, 0.f};
        HEAD_JT(acc0, 0)
        HEAD_JT(acc1, 1)
        HEAD_JT(acc2, 2)
        HEAD_JT(acc3, 3)
#pragma unroll
        for (int st = 1; st < 16; st <<= 1) {
#pragma unroll
            for (int r = 0; r < 4; r++) {
                h0[r] += __shfl_xor(h0[r], st, 64);
                h1[r] += __shfl_xor(h1[r], st, 64);
                h2[r] += __shfl_xor(h2[r], st, 64);
            }
        }
        if (lr == 0) {
#pragma unroll
            for (int r = 0; r < 4; r++) {
                int row = m0 + lh * 4 + r;
                out3[row * 3 + 0] = h0[r] + blin[0];
                out3[row * 3 + 1] = h1[r] + blin[1];
                out3[row * 3 + 2] = h2[r] + blin[2];
            }
        }
    }
}

extern "C" void kernel_launch(void* const* d_in, const int* in_sizes, int n_in,
                              void* d_out, int out_size, void* d_ws, size_t ws_size,
                              hipStream_t stream) {
    const float* x    = (const float*)d_in[0];
    const int*   eis  = (const int*)d_in[1];
    const int*   eid  = (const int*)d_in[2];
    const float* W1s  = (const float*)d_in[3];
    const float* b1s  = (const float*)d_in[4];
    const float* W1d  = (const float*)d_in[5];
    const float* b1d  = (const float*)d_in[6];
    const float* W2s  = (const float*)d_in[7];
    const float* b2s  = (const float*)d_in[8];
    const float* W2d  = (const float*)d_in[9];
    const float* b2d  = (const float*)d_in[10];
    const float* Wlin = (const float*)d_in[11];
    const float* blin = (const float*)d_in[12];

    const int N  = NN;
    const int Es = in_sizes[1] / 2;
    const int Ed = in_sizes[2] / 2;
    int Emax = (Es > Ed) ? Es : Ed;

    // workspace layout (4B units; every offset multiple of 4 units -> 16B aligned)
    int*   cntS  = (int*)d_ws;                  // [196]
    int*   cntD  = cntS + NBK;                  // [196]
    int*   baseS = cntD + NBK;                  // [200]
    int*   baseD = baseS + (NBK + 4);           // [200]
    int*   curS  = baseD + (NBK + 4);           // [196]
    int*   curD  = curS + NBK;                  // [196]
    int*   offsS = curD + NBK;                  // [50004]
    int*   offsD = offsS + (N + 4);             // [50004]
    float* dinvS = (float*)(offsD + (N + 4));   // [50000]
    float* dinvD = dinvS + N;                   // [50000]
    unsigned* recS = (unsigned*)(dinvD + N);    // [Es]
    unsigned* recD = recS + Es;                 // [Ed]
    unsigned* x16  = recD + Ed;                 // [N*32] fp16 x features
    unsigned* h16u = x16 + (size_t)N * 32;      // [N*32] fp16 layer-1 output
    unsigned* Abuf = h16u + (size_t)N * 32;     // [N*64] fp16 A matrix (aggS|aggD)
    unsigned short* Bp = (unsigned short*)(Abuf + (size_t)N * 64);  // [16384] halves
    unsigned short* h16 = (unsigned short*)h16u;

    // ---- prep: counts + feature convert + W pack in ONE dispatch ----
    hipMemsetAsync(cntS, 0, (size_t)2 * NBK * sizeof(int), stream);
    dim3 pgrid(3125, 3);  // x: 196 used by counts, 3125 by cvt (N*16/256), 64 by prep_w
    fat_prep<<<pgrid, 256, 0, stream>>>(eis, Es, eid, Ed, cntS, cntD,
                                        x, x16, N * 16, W1s, W1d, W2s, W2d, Bp);
    bucket_scan<<<2, 256, 0, stream>>>(cntS, cntD, baseS, baseD, curS, curD, offsS, offsD);
    dim3 egrid((Emax + CHUNK - 1) / CHUNK, 2);
    bucket_scatter<<<egrid, 256, 0, stream>>>(eis, Es, eid, Ed, curS, curD, recS, recD);
    dim3 fgrid(NBK, 2);
    bucket_finalize<<<fgrid, 256, 0, stream>>>(baseS, baseD, recS, recD, offsS, offsD,
                                               dinvS, dinvD);
    pack_rec<<<(Emax + 255) / 256, 256, 0, stream>>>(recS, Es, recD, Ed, dinvS, dinvD);

    dim3 ggrid((N + 15) / 16, 2);                     // 4 nodes/wave, rel = y
    int mtiles = (N + 15) / 16;                       // 3125 waves
    int applyBlocks = (mtiles * 64 + 255) / 256;      // 782 blocks

    // ---- layer 1 ----
    gather_agg<<<ggrid, 256, 0, stream>>>(offsS, recS, offsD, recD, x16,
                                          dinvS, dinvD, Abuf, N);
    apply_mfma<0><<<applyBlocks, 256, 0, stream>>>(Abuf, Bp, b1s, b1d,
                                                   nullptr, nullptr, h16, nullptr, N);

    // ---- layer 2 (head fused) ----
    gather_agg<<<ggrid, 256, 0, stream>>>(offsS, recS, offsD, recD, h16u,
                                          dinvS, dinvD, Abuf, N);
    apply_mfma<1><<<applyBlocks, 256, 0, stream>>>(Abuf, Bp + 8192, b2s, b2d,
                                                   Wlin, blin, nullptr, (float*)d_out, N);
}